// Round 6
// baseline (388.693 us; speedup 1.0000x reference)
//
#include <hip/hip_runtime.h>
#include <math.h>

#define TOK  1024
#define HID  1024
#define NEXP 16

typedef __attribute__((ext_vector_type(8))) short bf16x8;
typedef __attribute__((ext_vector_type(4))) float f32x4;

// swizzled-weight region offsets (in bf16 elements) — only SG/SU/SD used now
#define SW_GUT 0u
#define SW_GUV 16777216u
#define SW_DNT 25165824u
#define SW_DNV 33554432u
#define SW_SG  37748736u
#define SW_SU  38797312u
#define SW_SD  39845888u
#define SW_ELEMS 40894464ull
#define WS_SMALL 6554624ull                    // counts/lists/wlist + hbuf+hsh+Xbf
#define WS_FAST (WS_SMALL + SW_ELEMS * 2ull)   // = 88343552

__device__ __forceinline__ unsigned pack2(float f0, float f1) {
    union { float f; unsigned u; } a, b; a.f = f0; b.f = f1;
    return __builtin_amdgcn_perm(b.u + 0x8000u, a.u + 0x8000u, 0x07060302u);
}
__device__ __forceinline__ unsigned short f2bf(float f) {
    union { float f; unsigned u; } v; v.f = f;
    return (unsigned short)((v.u + 0x8000u) >> 16);
}
__device__ __forceinline__ f32x4 ntload4(const float* p) {
    return __builtin_nontemporal_load((const f32x4*)p);
}
// pack 8 fp32 (consecutive k) into a bf16x8 B-fragment (k-pair dwords)
__device__ __forceinline__ bf16x8 packfrag(const float* v) {
    union { bf16x8 b; unsigned d[4]; } u;
    u.d[0] = pack2(v[0], v[1]); u.d[1] = pack2(v[2], v[3]);
    u.d[2] = pack2(v[4], v[5]); u.d[3] = pack2(v[6], v[7]);
    return u.b;
}

// ---------------- init: zero counts + zero final-out region ----------------
__global__ void k_init(float* __restrict__ out, int* __restrict__ counts) {
    size_t i = (size_t)blockIdx.x * blockDim.x + threadIdx.x;   // 262144 float4
    ((float4*)out)[i] = make_float4(0.f, 0.f, 0.f, 0.f);
    if (blockIdx.x == 0 && threadIdx.x < 32) counts[threadIdx.x] = 0;
}

// ---------------- router: 1 wave per token (fp32 exact) + Xbf emission -----
__global__ __launch_bounds__(64)
void k_router(const float* __restrict__ x, const int* __restrict__ tt,
              const float* __restrict__ rw_t, const float* __restrict__ b_t,
              const float* __restrict__ rw_v, const float* __restrict__ b_v,
              float* __restrict__ out_logits,
              int* __restrict__ counts, int* __restrict__ lists,
              float* __restrict__ wlist, unsigned short* __restrict__ Xbf)
{
    const int t = blockIdx.x;
    const int lane = threadIdx.x;
    const bool vis = (tt[t] != 0);
    const float* rw   = vis ? rw_v : rw_t;
    const float* bias = vis ? b_v  : b_t;
    const float* xr = x + (size_t)t * HID;

#pragma unroll
    for (int jj = 0; jj < 2; ++jj) {
        int j0 = jj * 512 + lane * 8;
        float4 lo = *(const float4*)(xr + j0);
        float4 hi = *(const float4*)(xr + j0 + 4);
        union { bf16x8 v; unsigned d[4]; } u;
        u.d[0] = pack2(lo.x, lo.y); u.d[1] = pack2(lo.z, lo.w);
        u.d[2] = pack2(hi.x, hi.y); u.d[3] = pack2(hi.z, hi.w);
        *(bf16x8*)(Xbf + (size_t)t * HID + j0) = u.v;
    }

    float acc[NEXP];
#pragma unroll
    for (int e = 0; e < NEXP; ++e) acc[e] = 0.f;
    for (int j = 0; j < HID; j += 64) {
        const float xv = xr[j + lane];
#pragma unroll
        for (int e = 0; e < NEXP; ++e)
            acc[e] = fmaf(xv, rw[(size_t)e * HID + j + lane], acc[e]);
    }
#pragma unroll
    for (int e = 0; e < NEXP; ++e) {
        float v = acc[e];
#pragma unroll
        for (int off = 32; off; off >>= 1) v += __shfl_xor(v, off);
        acc[e] = v;
    }
    if (lane < NEXP) out_logits[(size_t)t * NEXP + lane] = acc[lane];

    if (lane == 0) {
        float mx = acc[0];
#pragma unroll
        for (int e = 1; e < NEXP; ++e) mx = fmaxf(mx, acc[e]);
        float p[NEXP], s = 0.f;
#pragma unroll
        for (int e = 0; e < NEXP; ++e) { p[e] = expf(acc[e] - mx); s += p[e]; }
        const float inv = 1.f / s;
#pragma unroll
        for (int e = 0; e < NEXP; ++e) p[e] *= inv;

        int s1 = 0; float v1 = p[0] + bias[0];
#pragma unroll
        for (int e = 1; e < NEXP; ++e) {
            float c = p[e] + bias[e];
            if (c > v1) { v1 = c; s1 = e; }
        }
        int s2 = -1; float v2 = -1e30f;
#pragma unroll
        for (int e = 0; e < NEXP; ++e) {
            if (e == s1) continue;
            float c = p[e] + bias[e];
            if (c > v2) { v2 = c; s2 = e; }
        }
        float w1 = p[s1], w2 = p[s2];
        float sw = fmaxf(w1 + w2, 1e-12f);
        w1 /= sw; w2 /= sw;

        const int base = vis ? NEXP : 0;
        int pos1 = atomicAdd(&counts[base + s1], 1);
        lists[(base + s1) * TOK + pos1] = t * 2 + 0;
        wlist[(base + s1) * TOK + pos1] = w1;
        int pos2 = atomicAdd(&counts[base + s2], 1);
        lists[(base + s2) * TOK + pos2] = t * 2 + 1;
        wlist[(base + s2) * TOK + pos2] = w2;
    }
}

// ---------------- shared-weight convert/swizzle (sg/su/sd only) ------------
// 384 panels (128 per matrix), 2 panels per block -> 192 blocks. K=N=1024.
// NT fp32 reads (single-use); pack-before-LDS kpair dwords (v3 structure).
__device__ __forceinline__ void conv_decode_sh(
    int bid, const float* sg, const float* su, const float* sd,
    unsigned short* sw, const float*& src, unsigned short*& dst, int& c, int& p)
{
    int i = bid & 127; c = i >> 2; p = i & 3;
    int m = bid >> 7;
    src = (m == 0) ? sg : (m == 1) ? su : sd;
    dst = sw + ((m == 0) ? SW_SG : (m == 1) ? SW_SU : SW_SD);
}

__global__ __launch_bounds__(256)
void k_conv(const float* __restrict__ sg, const float* __restrict__ su,
            const float* __restrict__ sd, unsigned short* __restrict__ sw)
{
    __shared__ unsigned ls[16 * 258];
    const int tid = threadIdx.x;
    const int b0 = blockIdx.x * 2;

    const float *sA, *sB; unsigned short *dA, *dB;
    int cA, pA, cB, pB;
    conv_decode_sh(b0 + 0, sg, su, sd, sw, sA, dA, cA, pA);
    conv_decode_sh(b0 + 1, sg, su, sd, sw, sB, dB, cB, pB);

    f32x4 Ra[8], Rb[8];
#pragma unroll
    for (int i = 0; i < 4; ++i) {
        int u = tid + i * 256; int kp = u >> 6, c4 = u & 63;
        const float* r0 = sA + (size_t)(cA * 32 + 2 * kp) * 1024 + pA * 256 + c4 * 4;
        Ra[2 * i]     = ntload4(r0);
        Ra[2 * i + 1] = ntload4(r0 + 1024);
    }
#pragma unroll
    for (int i = 0; i < 4; ++i) {
        int u = tid + i * 256; int kp = u >> 6, c4 = u & 63;
        const float* r0 = sB + (size_t)(cB * 32 + 2 * kp) * 1024 + pB * 256 + c4 * 4;
        Rb[2 * i]     = ntload4(r0);
        Rb[2 * i + 1] = ntload4(r0 + 1024);
    }

    // ---- panel A ----
#pragma unroll
    for (int i = 0; i < 4; ++i) {
        int u = tid + i * 256; int kp = u >> 6, c4 = u & 63;
        unsigned* lp = &ls[kp * 258 + c4 * 4];
        f32x4 a = Ra[2 * i], b = Ra[2 * i + 1];
        lp[0] = pack2(a[0], b[0]); lp[1] = pack2(a[1], b[1]);
        lp[2] = pack2(a[2], b[2]); lp[3] = pack2(a[3], b[3]);
    }
    __syncthreads();
#pragma unroll
    for (int i = 0; i < 4; ++i) {
        int u = tid + i * 256;
        int tt = u >> 6, l = u & 63;
        int q = l >> 4, lm = l & 15;
        int col = tt * 16 + lm;
        unsigned d0 = ls[(q * 4 + 0) * 258 + col];
        unsigned d1 = ls[(q * 4 + 1) * 258 + col];
        unsigned d2 = ls[(q * 4 + 2) * 258 + col];
        unsigned d3 = ls[(q * 4 + 3) * 258 + col];
        size_t off = ((size_t)((pA * 16 + tt) * 32 + cA) * 64 + l) * 8;
        *(uint4*)(dA + off) = make_uint4(d0, d1, d2, d3);
    }
    __syncthreads();

    // ---- panel B ----
#pragma unroll
    for (int i = 0; i < 4; ++i) {
        int u = tid + i * 256; int kp = u >> 6, c4 = u & 63;
        unsigned* lp = &ls[kp * 258 + c4 * 4];
        f32x4 a = Rb[2 * i], b = Rb[2 * i + 1];
        lp[0] = pack2(a[0], b[0]); lp[1] = pack2(a[1], b[1]);
        lp[2] = pack2(a[2], b[2]); lp[3] = pack2(a[3], b[3]);
    }
    __syncthreads();
#pragma unroll
    for (int i = 0; i < 4; ++i) {
        int u = tid + i * 256;
        int tt = u >> 6, l = u & 63;
        int q = l >> 4, lm = l & 15;
        int col = tt * 16 + lm;
        unsigned d0 = ls[(q * 4 + 0) * 258 + col];
        unsigned d1 = ls[(q * 4 + 1) * 258 + col];
        unsigned d2 = ls[(q * 4 + 2) * 258 + col];
        unsigned d3 = ls[(q * 4 + 3) * 258 + col];
        size_t off = ((size_t)((pB * 16 + tt) * 32 + cB) * 64 + l) * 8;
        *(uint4*)(dB + off) = make_uint4(d0, d1, d2, d3);
    }
}

// ---------------- gate+up GEMM + silu -------------------------------------
// z<32 (experts): DIRECT fp32 gather — lane (col=lm, kq=q) gathers its
// B-fragment with 8 strided dword loads (4 full 64B lines per wave-instr),
// packs in-register. No conv, no LDS, weights read ONCE from HBM.
// z==32 (shared): stream pre-swizzled bf16 frags (16x m-reuse via L3).
__global__ __launch_bounds__(256)
void k_gu3(const unsigned short* __restrict__ Xbf,
           const float* __restrict__ gut, const float* __restrict__ guv,
           const unsigned short* __restrict__ sw,
           const int* __restrict__ counts, const int* __restrict__ lists,
           unsigned short* __restrict__ hbuf, unsigned short* __restrict__ hsh)
{
    const int z = blockIdx.z;
    const int tid = threadIdx.x;
    const int w = tid >> 6, lane = tid & 63;
    const int lm = lane & 15, q = lane >> 4;
    const int ko = q * 8;
    const int xI = blockIdx.x * 16, m0 = blockIdx.y * 64;
    __shared__ int s_aid[64];

    if (z == 32) {
        if (tid < 64) s_aid[tid] = m0 + tid;
        __syncthreads();
        int aidA = s_aid[w * 16 + lm];
        const unsigned short* arow = Xbf + (size_t)aidA * HID;
        const int tg = xI >> 4;
        const unsigned short* pg = sw + SW_SG + (size_t)tg * 32 * 512 + lane * 8;
        const unsigned short* pu = sw + SW_SU + (size_t)tg * 32 * 512 + lane * 8;
        f32x4 accG = {}, accU = {};
        bf16x8 Bg[4], Bu[4], Af[4];
#pragma unroll
        for (int p = 0; p < 4; ++p) {
            Bg[p] = *(const bf16x8*)(pg + p * 512);
            Bu[p] = *(const bf16x8*)(pu + p * 512);
            Af[p] = *(const bf16x8*)(arow + p * 32 + ko);
        }
        for (int cc = 0; cc < 32; cc += 4) {
#pragma unroll
            for (int p = 0; p < 4; ++p) {
                accG = __builtin_amdgcn_mfma_f32_16x16x32_bf16(Af[p], Bg[p], accG, 0, 0, 0);
                accU = __builtin_amdgcn_mfma_f32_16x16x32_bf16(Af[p], Bu[p], accU, 0, 0, 0);
                int cp = cc + p + 4; if (cp > 31) cp = 31;
                Bg[p] = *(const bf16x8*)(pg + cp * 512);
                Bu[p] = *(const bf16x8*)(pu + cp * 512);
                Af[p] = *(const bf16x8*)(arow + cp * 32 + ko);
            }
        }
        const int i = xI + lm;
#pragma unroll
        for (int r = 0; r < 4; ++r) {
            int row = w * 16 + q * 4 + r;
            int aid = s_aid[row];
            float g = accG[r], uu = accU[r];
            float h = g / (1.f + __expf(-g)) * uu;
            hsh[(size_t)aid * 1024 + i] = f2bf(h);
        }
        return;
    }

    const int M = counts[z];
    int I, str; const float* base;
    if (z < 16) { I = 512; str = 1024; base = gut + (size_t)z * 1048576; }
    else        { I = 256; str = 512;  base = guv + (size_t)(z - 16) * 524288; }
    if (xI >= I || m0 >= M) return;

    if (tid < 64) {
        int r = m0 + tid;
        s_aid[tid] = (r < M) ? lists[z * TOK + r] : -1;
    }
    __syncthreads();

    int aidA = s_aid[w * 16 + lm];
    const unsigned short* arow = Xbf + (size_t)(aidA < 0 ? 0 : (aidA >> 1)) * HID;

    const float* pw[8];
#pragma unroll
    for (int j = 0; j < 8; ++j)
        pw[j] = base + (size_t)(ko + j) * str + xI + lm;
    const size_t cstep = (size_t)32 * str;     // elements per k-chunk

    f32x4 accG = {}, accU = {};
    float G0[8], U0[8], G1[8], U1[8];
    bf16x8 A0, A1;
#pragma unroll
    for (int j = 0; j < 8; ++j) { G0[j] = pw[j][0]; U0[j] = pw[j][(size_t)I]; }
    A0 = *(const bf16x8*)(arow + ko);
    for (int c = 0; c < 32; c += 2) {
        {
            const size_t o = (size_t)(c + 1) * cstep;
#pragma unroll
            for (int j = 0; j < 8; ++j) { G1[j] = pw[j][o]; U1[j] = pw[j][o + I]; }
            A1 = *(const bf16x8*)(arow + (c + 1) * 32 + ko);
        }
        accG = __builtin_amdgcn_mfma_f32_16x16x32_bf16(A0, packfrag(G0), accG, 0, 0, 0);
        accU = __builtin_amdgcn_mfma_f32_16x16x32_bf16(A0, packfrag(U0), accU, 0, 0, 0);
        if (c + 2 < 32) {
            const size_t o = (size_t)(c + 2) * cstep;
#pragma unroll
            for (int j = 0; j < 8; ++j) { G0[j] = pw[j][o]; U0[j] = pw[j][o + I]; }
            A0 = *(const bf16x8*)(arow + (c + 2) * 32 + ko);
        }
        accG = __builtin_amdgcn_mfma_f32_16x16x32_bf16(A1, packfrag(G1), accG, 0, 0, 0);
        accU = __builtin_amdgcn_mfma_f32_16x16x32_bf16(A1, packfrag(U1), accU, 0, 0, 0);
    }

    const int i = xI + lm;
#pragma unroll
    for (int r = 0; r < 4; ++r) {
        int row = w * 16 + q * 4 + r;
        int aid = s_aid[row];
        if (aid < 0) continue;
        float g = accG[r], uu = accU[r];
        float h = g / (1.f + __expf(-g)) * uu;
        hbuf[(size_t)aid * 512 + i] = f2bf(h);
    }
}

// ---------------- down GEMM ------------------------------------------------
// z<32: direct fp32 gather (weights read once). z==32: swz stream.
__global__ __launch_bounds__(256)
void k_down3(const unsigned short* __restrict__ hbuf, const unsigned short* __restrict__ hsh,
             const float* __restrict__ dnt, const float* __restrict__ dnv,
             const unsigned short* __restrict__ sw,
             const int* __restrict__ counts, const int* __restrict__ lists,
             const float* __restrict__ wlist, float* __restrict__ out)
{
    const int z = blockIdx.z;
    const int tid = threadIdx.x;
    const int w = tid >> 6, lane = tid & 63;
    const int lm = lane & 15, q = lane >> 4;
    const int ko = q * 8;
    const int n0 = blockIdx.x * 16, m0 = blockIdx.y * 64;
    __shared__ int s_aid[64];
    __shared__ float s_w[64];

    if (z == 32) {
        if (tid < 64) s_aid[tid] = m0 + tid;
        __syncthreads();
        int aidA = s_aid[w * 16 + lm];
        const unsigned short* hrow = hsh + (size_t)aidA * 1024;
        const unsigned short* pb = sw + SW_SD + (size_t)blockIdx.x * 32 * 512 + lane * 8;
        f32x4 acc = {};
        bf16x8 Bt[4], Af[4];
#pragma unroll
        for (int p = 0; p < 4; ++p) {
            Bt[p] = *(const bf16x8*)(pb + p * 512);
            Af[p] = *(const bf16x8*)(hrow + p * 32 + ko);
        }
        for (int cc = 0; cc < 32; cc += 4) {
#pragma unroll
            for (int p = 0; p < 4; ++p) {
                acc = __builtin_amdgcn_mfma_f32_16x16x32_bf16(Af[p], Bt[p], acc, 0, 0, 0);
                int cp = cc + p + 4; if (cp > 31) cp = 31;
                Bt[p] = *(const bf16x8*)(pb + cp * 512);
                Af[p] = *(const bf16x8*)(hrow + cp * 32 + ko);
            }
        }
        const int col = n0 + lm;
#pragma unroll
        for (int r = 0; r < 4; ++r) {
            int row = w * 16 + q * 4 + r;
            int tok = s_aid[row];
            atomicAdd(&out[(size_t)tok * HID + col], acc[r]);
        }
        return;
    }

    const int M = counts[z];
    if (m0 >= M) return;
    int K; const float* base;
    if (z < 16) { K = 512; base = dnt + (size_t)z * 524288; }
    else        { K = 256; base = dnv + (size_t)(z - 16) * 262144; }

    if (tid < 64) {
        int r = m0 + tid;
        if (r < M) { s_aid[tid] = lists[z * TOK + r]; s_w[tid] = wlist[z * TOK + r]; }
        else       { s_aid[tid] = -1; s_w[tid] = 0.f; }
    }
    __syncthreads();

    int aidA = s_aid[w * 16 + lm];
    const unsigned short* hrow = hbuf + (size_t)(aidA < 0 ? 0 : aidA) * 512;

    const float* pw[8];
#pragma unroll
    for (int j = 0; j < 8; ++j)
        pw[j] = base + (size_t)(ko + j) * 1024 + n0 + lm;
    const size_t cstep = (size_t)32 * 1024;
    const int KC = K >> 5;                     // 16 or 8 (even)

    f32x4 acc = {};
    float B0[8], B1[8];
    bf16x8 A0, A1;
#pragma unroll
    for (int j = 0; j < 8; ++j) B0[j] = pw[j][0];
    A0 = *(const bf16x8*)(hrow + ko);
    for (int c = 0; c < KC; c += 2) {
        const size_t o1 = (size_t)(c + 1) * cstep;
#pragma unroll
        for (int j = 0; j < 8; ++j) B1[j] = pw[j][o1];
        A1 = *(const bf16x8*)(hrow + (c + 1) * 32 + ko);
        acc = __builtin_amdgcn_mfma_f32_16x16x32_bf16(A0, packfrag(B0), acc, 0, 0, 0);
        if (c + 2 < KC) {
            const size_t o2 = (size_t)(c + 2) * cstep;
#pragma unroll
            for (int j = 0; j < 8; ++j) B0[j] = pw[j][o2];
            A0 = *(const bf16x8*)(hrow + (c + 2) * 32 + ko);
        }
        acc = __builtin_amdgcn_mfma_f32_16x16x32_bf16(A1, packfrag(B1), acc, 0, 0, 0);
    }

    const int col = n0 + lm;
#pragma unroll
    for (int r = 0; r < 4; ++r) {
        int row = w * 16 + q * 4 + r;
        int aid = s_aid[row];
        if (aid < 0) continue;
        atomicAdd(&out[(size_t)(aid >> 1) * HID + col], s_w[row] * acc[r]);
    }
}

// ================= fallback path (small ws): r5 kernels, uncapped bounds ===
__global__ __launch_bounds__(256)
void k_gu_fb(const unsigned short* __restrict__ Xbf,
             const float* __restrict__ gut, const float* __restrict__ guv,
             const float* __restrict__ sg, const float* __restrict__ su,
             const int* __restrict__ counts, const int* __restrict__ lists,
             unsigned short* __restrict__ hbuf, unsigned short* __restrict__ hsh)
{
    const int z = blockIdx.z;
    int M, I, str;
    const float *Wg, *Wu;
    if (z == 32) { M = TOK; I = 1024; str = 1024; Wg = sg; Wu = su; }
    else {
        M = counts[z];
        const int mod = z >> 4, e = z & 15;
        I = mod ? 256 : 512; str = 2 * I;
        const float* base = mod ? (guv + (size_t)e * HID * 512)
                                : (gut + (size_t)e * HID * 1024);
        Wg = base; Wu = base + I;
    }
    const int xI = blockIdx.x * 64;
    const int m0 = blockIdx.y * 64;
    if (xI >= I || m0 >= M) return;

    __shared__ float bs[8192];
    __shared__ int s_aid[64];
    const int tid = threadIdx.x;
    const int wid = tid >> 6, lane = tid & 63;
    const int lm = lane & 15, q = lane >> 4;

    if (tid < 64) {
        int r = m0 + tid;
        s_aid[tid] = (z == 32) ? r : ((r < M) ? lists[z * TOK + r] : -1);
    }
    __syncthreads();

    const unsigned short* arow[4];
#pragma unroll
    for (int s = 0; s < 4; ++s) {
        int aid = s_aid[s * 16 + lm];
        int tr = (z == 32) ? aid : (aid < 0 ? 0 : (aid >> 1));
        arow[s] = Xbf + (size_t)tr * HID;
    }
    int urow[8], uc4[8], scell[8];
#pragma unroll
    for (int r = 0; r < 8; ++r) {
        int u = r * 256 + tid;
        int k = u >> 5;
        urow[r] = k; uc4[r] = u & 31;
        scell[r] = k * 32 + ((u & 31) ^ (((k >> 3) & 1) << 2));
    }
    int fidx[2];
#pragma unroll
    for (int reg = 0; reg < 2; ++reg) {
        int c = reg * 64 + wid * 16 + lm;
        fidx[reg] = (q * 8) * 128 + (((c >> 2) ^ ((q & 1) << 2)) * 4 + (c & 3));
    }
    float4 R[8];
#pragma unroll
    for (int r = 0; r < 8; ++r) {
        int c4 = uc4[r];
        const float* gp = (c4 < 16) ? (Wg + (size_t)urow[r] * str + xI + c4 * 4)
                                    : (Wu + (size_t)urow[r] * str + xI + (c4 - 16) * 4);
        R[r] = *(const float4*)gp;
    }
    f32x4 accG[4] = {}, accU[4] = {};
    for (int kc = 0; kc < 16; ++kc) {
        if (kc) __syncthreads();
#pragma unroll
        for (int r = 0; r < 8; ++r)
            *(float4*)&bs[scell[r] * 4] = R[r];
        __syncthreads();
        bf16x8 af[2][4];
        const int kg = kc * 64 + q * 8;
#pragma unroll
        for (int s = 0; s < 4; ++s) {
            af[0][s] = *(const bf16x8*)(arow[s] + kg);
            af[1][s] = *(const bf16x8*)(arow[s] + kg + 32);
        }
        if (kc + 1 < 16) {
            const int k0 = (kc + 1) * 64;
#pragma unroll
            for (int r = 0; r < 8; ++r) {
                int c4 = uc4[r];
                const float* gp = (c4 < 16) ? (Wg + (size_t)(k0 + urow[r]) * str + xI + c4 * 4)
                                            : (Wu + (size_t)(k0 + urow[r]) * str + xI + (c4 - 16) * 4);
                R[r] = *(const float4*)gp;
            }
        }
#pragma unroll
        for (int ks2 = 0; ks2 < 2; ++ks2) {
            const int ks = ks2 * 32;
            bf16x8 bg, bu;
            {
                float b[8];
#pragma unroll
                for (int j = 0; j < 8; ++j) b[j] = bs[fidx[0] + (ks + j) * 128];
                union { bf16x8 v; unsigned d[4]; } u;
                u.d[0] = pack2(b[0], b[1]); u.d[1] = pack2(b[2], b[3]);
                u.d[2] = pack2(b[4], b[5]); u.d[3] = pack2(b[6], b[7]);
                bg = u.v;
            }
            {
                float b[8];
#pragma unroll
                for (int j = 0; j < 8; ++j) b[j] = bs[fidx[1] + (ks + j) * 128];
                union { bf16x8 v; unsigned d[4]; } u;
                u.d[0] = pack2(b[0], b[1]); u.d[1] = pack2(b[2], b[3]);
                u.d[2] = pack2(b[4], b[5]); u.d[3] = pack2(b[6], b[7]);
                bu = u.v;
            }
#pragma unroll
            for (int s = 0; s < 4; ++s) {
                accG[s] = __builtin_amdgcn_mfma_f32_16x16x32_bf16(af[ks2][s], bg, accG[s], 0, 0, 0);
                accU[s] = __builtin_amdgcn_mfma_f32_16x16x32_bf16(af[ks2][s], bu, accU[s], 0, 0, 0);
            }
        }
    }
    const int i = xI + wid * 16 + lm;
#pragma unroll
    for (int s = 0; s < 4; ++s)
#pragma unroll
        for (int r = 0; r < 4; ++r) {
            int row = s * 16 + q * 4 + r;
            int aid = s_aid[row];
            if (aid < 0) continue;
            float g = accG[s][r], uu = accU[s][r];
            float h = g / (1.f + __expf(-g)) * uu;
            if (z == 32) hsh[(size_t)aid * 1024 + i] = f2bf(h);
            else         hbuf[(size_t)aid * 512 + i] = f2bf(h);
        }
}

__global__ __launch_bounds__(256)
void k_down_fb(const unsigned short* __restrict__ hbuf, const unsigned short* __restrict__ hsh,
               const float* __restrict__ dnt, const float* __restrict__ dnv,
               const float* __restrict__ sd,
               const int* __restrict__ counts, const int* __restrict__ lists,
               const float* __restrict__ wlist, float* __restrict__ out)
{
    const int z = blockIdx.z;
    int M, K;
    const float* W;
    if (z == 32) { M = TOK; K = 1024; W = sd; }
    else {
        M = counts[z];
        const int mod = z >> 4, e = z & 15;
        K = mod ? 256 : 512;
        W = mod ? (dnv + (size_t)e * 256 * 1024) : (dnt + (size_t)e * 512 * 1024);
    }
    const int n0 = blockIdx.x * 128;
    const int m0 = blockIdx.y * 64;
    if (m0 >= M) return;

    __shared__ float bs[8192];
    __shared__ int s_aid[64];
    __shared__ float s_w[64];
    const int tid = threadIdx.x;
    const int wid = tid >> 6, lane = tid & 63;
    const int lm = lane & 15, q = lane >> 4;

    if (tid < 64) {
        int r = m0 + tid;
        if (z == 32)    { s_aid[tid] = r; s_w[tid] = 1.f; }
        else if (r < M) { s_aid[tid] = lists[z * TOK + r]; s_w[tid] = wlist[z * TOK + r]; }
        else            { s_aid[tid] = -1; s_w[tid] = 0.f; }
    }
    __syncthreads();

    const unsigned short* hrow[4];
#pragma unroll
    for (int s = 0; s < 4; ++s) {
        int aid = s_aid[s * 16 + lm];
        hrow[s] = (z == 32) ? (hsh + (size_t)aid * 1024)
                            : (hbuf + (size_t)(aid < 0 ? 0 : aid) * 512);
    }
    int urow[8], uc4[8], scell[8];
#pragma unroll
    for (int r = 0; r < 8; ++r) {
        int u = r * 256 + tid;
        int k = u >> 5;
        urow[r] = k; uc4[r] = u & 31;
        scell[r] = k * 32 + ((u & 31) ^ (((k >> 3) & 1) << 2));
    }
    int fidx[2];
#pragma unroll
    for (int t = 0; t < 2; ++t) {
        int c = wid * 32 + t * 16 + lm;
        fidx[t] = (q * 8) * 128 + (((c >> 2) ^ ((q & 1) << 2)) * 4 + (c & 3));
    }
    float4 R[8];
#pragma unroll
    for (int r = 0; r < 8; ++r)
        R[r] = *(const float4*)(W + (size_t)urow[r] * 1024 + n0 + uc4[r] * 4);

    f32x4 acc[4][2] = {};
    const int NC = K >> 6;
    for (int kc = 0; kc < NC; ++kc) {
        if (kc) __syncthreads();
#pragma unroll
        for (int r = 0; r < 8; ++r)
            *(float4*)&bs[scell[r] * 4] = R[r];
        __syncthreads();
        bf16x8 af[2][4];
        const int kg = kc * 64 + q * 8;
#pragma unroll
        for (int s = 0; s < 4; ++s) {
            af[0][s] = *(const bf16x8*)(hrow[s] + kg);
            af[1][s] = *(const bf16x8*)(hrow[s] + kg + 32);
        }
        if (kc + 1 < NC) {
            const int k0 = (kc + 1) * 64;
#pragma unroll
            for (int r = 0; r < 8; ++r)
                R[r] = *(const float4*)(W + (size_t)(k0 + urow[r]) * 1024 + n0 + uc4[r] * 4);
        }
#pragma unroll
        for (int ks2 = 0; ks2 < 2; ++ks2) {
            const int ks = ks2 * 32;
            bf16x8 bt[2];
#pragma unroll
            for (int t = 0; t < 2; ++t) {
                float b[8];
#pragma unroll
                for (int j = 0; j < 8; ++j) b[j] = bs[fidx[t] + (ks + j) * 128];
                union { bf16x8 v; unsigned d[4]; } u;
                u.d[0] = pack2(b[0], b[1]); u.d[1] = pack2(b[2], b[3]);
                u.d[2] = pack2(b[4], b[5]); u.d[3] = pack2(b[6], b[7]);
                bt[t] = u.v;
            }
#pragma unroll
            for (int s = 0; s < 4; ++s)
#pragma unroll
                for (int t = 0; t < 2; ++t)
                    acc[s][t] = __builtin_amdgcn_mfma_f32_16x16x32_bf16(af[ks2][s], bt[t], acc[s][t], 0, 0, 0);
        }
    }
#pragma unroll
    for (int s = 0; s < 4; ++s)
#pragma unroll
        for (int r = 0; r < 4; ++r) {
            int row = s * 16 + q * 4 + r;
            int aid = s_aid[row];
            if (aid < 0) continue;
            int tok = (z == 32) ? aid : (aid >> 1);
            float w = s_w[row];
#pragma unroll
            for (int t = 0; t < 2; ++t) {
                int col = n0 + wid * 32 + t * 16 + lm;
                atomicAdd(&out[(size_t)tok * HID + col], w * acc[s][t][r]);
            }
        }
}

extern "C" void kernel_launch(void* const* d_in, const int* in_sizes, int n_in,
                              void* d_out, int out_size, void* d_ws, size_t ws_size,
                              hipStream_t stream)
{
    const float* x    = (const float*)d_in[0];
    const int*   tt   = (const int*)d_in[1];
    const float* rw_t = (const float*)d_in[2];
    const float* b_t  = (const float*)d_in[3];
    const float* gu_t = (const float*)d_in[4];
    const float* dn_t = (const float*)d_in[5];
    const float* rw_v = (const float*)d_in[6];
    const float* b_v  = (const float*)d_in[7];
    const float* gu_v = (const float*)d_in[8];
    const float* dn_v = (const float*)d_in[9];
    const float* sg   = (const float*)d_in[10];
    const float* su   = (const float*)d_in[11];
    const float* sd   = (const float*)d_in[12];
    float* out = (float*)d_out;
    float* out_logits = out + (size_t)TOK * HID;

    char* ws = (char*)d_ws;
    int*   counts = (int*)ws;                                   // 32 ints
    int*   lists  = (int*)(ws + 1024);                          // 32*1024 ints
    float* wlist  = (float*)(ws + 1024 + 32 * TOK * 4);         // 32*1024 floats
    unsigned short* hbuf = (unsigned short*)(ws + 1024 + 64 * TOK * 4);  // 2048x512 bf16
    unsigned short* hsh  = hbuf + (size_t)2048 * 512;                    // 1024x1024 bf16
    unsigned short* Xbf  = hsh + (size_t)1024 * 1024;                    // 1024x1024 bf16
    unsigned short* swz  = Xbf + (size_t)1024 * 1024;                    // swizzled shared weights

    hipLaunchKernelGGL(k_init, dim3(1024), dim3(256), 0, stream, out, counts);
    hipLaunchKernelGGL(k_router, dim3(TOK), dim3(64), 0, stream,
                       x, tt, rw_t, b_t, rw_v, b_v, out_logits, counts, lists, wlist, Xbf);
    if (ws_size >= WS_FAST) {
        hipLaunchKernelGGL(k_conv, dim3(192), dim3(256), 0, stream,
                           sg, su, sd, swz);
        hipLaunchKernelGGL(k_gu3, dim3(64, 16, 33), dim3(256), 0, stream,
                           Xbf, gu_t, gu_v, swz, counts, lists, hbuf, hsh);
        hipLaunchKernelGGL(k_down3, dim3(64, 16, 33), dim3(256), 0, stream,
                           hbuf, hsh, dn_t, dn_v, swz, counts, lists, wlist, out);
    } else {
        hipLaunchKernelGGL(k_gu_fb, dim3(16, 16, 33), dim3(256), 0, stream,
                           Xbf, gu_t, gu_v, sg, su, counts, lists, hbuf, hsh);
        hipLaunchKernelGGL(k_down_fb, dim3(8, 16, 33), dim3(256), 0, stream,
                           hbuf, hsh, dn_t, dn_v, sd, counts, lists, wlist, out);
    }
}

// Round 7
// 308.396 us; speedup vs baseline: 1.2604x; 1.2604x over previous
//
#include <hip/hip_runtime.h>
#include <math.h>

#define TOK  1024
#define HID  1024
#define NEXP 16

typedef __attribute__((ext_vector_type(8))) short bf16x8;
typedef __attribute__((ext_vector_type(4))) float f32x4;

// swizzled-weight region offsets (in bf16 elements)
#define SW_GUT 0u
#define SW_GUV 16777216u
#define SW_DNT 25165824u
#define SW_DNV 33554432u
#define SW_SG  37748736u
#define SW_SU  38797312u
#define SW_SD  39845888u
#define SW_ELEMS 40894464ull
#define WS_SMALL 6554624ull                    // counts/lists/wlist + hbuf+hsh+Xbf
#define WS_FAST (WS_SMALL + SW_ELEMS * 2ull)   // = 88343552

__device__ __forceinline__ unsigned pack2(float f0, float f1) {
    union { float f; unsigned u; } a, b; a.f = f0; b.f = f1;
    return __builtin_amdgcn_perm(b.u + 0x8000u, a.u + 0x8000u, 0x07060302u);
}
__device__ __forceinline__ unsigned short f2bf(float f) {
    union { float f; unsigned u; } v; v.f = f;
    return (unsigned short)((v.u + 0x8000u) >> 16);
}
__device__ __forceinline__ f32x4 ntload4(const float* p) {
    return __builtin_nontemporal_load((const f32x4*)p);
}
// async global->LDS DMA, 16 B/lane: dst(lane l) = lptr + l*16. No VGPR
// round-trip -> the compiler cannot sink these; they stay in flight until
// the single barrier drain. (guide §5: the tool for pipeline-collapse.)
__device__ __forceinline__ void lds_dma16(const unsigned short* g, unsigned short* l) {
    __builtin_amdgcn_global_load_lds(
        (const __attribute__((address_space(1))) void*)g,
        (__attribute__((address_space(3))) void*)l, 16, 0, 0);
}

// ---------------- init: zero counts + zero final-out region ----------------
__global__ void k_init(float* __restrict__ out, int* __restrict__ counts) {
    size_t i = (size_t)blockIdx.x * blockDim.x + threadIdx.x;   // 262144 float4
    ((float4*)out)[i] = make_float4(0.f, 0.f, 0.f, 0.f);
    if (blockIdx.x == 0 && threadIdx.x < 32) counts[threadIdx.x] = 0;
}

// ---------------- router: 1 wave per token (fp32 exact) + Xbf emission -----
__global__ __launch_bounds__(64)
void k_router(const float* __restrict__ x, const int* __restrict__ tt,
              const float* __restrict__ rw_t, const float* __restrict__ b_t,
              const float* __restrict__ rw_v, const float* __restrict__ b_v,
              float* __restrict__ out_logits,
              int* __restrict__ counts, int* __restrict__ lists,
              float* __restrict__ wlist, unsigned short* __restrict__ Xbf)
{
    const int t = blockIdx.x;
    const int lane = threadIdx.x;
    const bool vis = (tt[t] != 0);
    const float* rw   = vis ? rw_v : rw_t;
    const float* bias = vis ? b_v  : b_t;
    const float* xr = x + (size_t)t * HID;

#pragma unroll
    for (int jj = 0; jj < 2; ++jj) {
        int j0 = jj * 512 + lane * 8;
        float4 lo = *(const float4*)(xr + j0);
        float4 hi = *(const float4*)(xr + j0 + 4);
        union { bf16x8 v; unsigned d[4]; } u;
        u.d[0] = pack2(lo.x, lo.y); u.d[1] = pack2(lo.z, lo.w);
        u.d[2] = pack2(hi.x, hi.y); u.d[3] = pack2(hi.z, hi.w);
        *(bf16x8*)(Xbf + (size_t)t * HID + j0) = u.v;
    }

    float acc[NEXP];
#pragma unroll
    for (int e = 0; e < NEXP; ++e) acc[e] = 0.f;
    for (int j = 0; j < HID; j += 64) {
        const float xv = xr[j + lane];
#pragma unroll
        for (int e = 0; e < NEXP; ++e)
            acc[e] = fmaf(xv, rw[(size_t)e * HID + j + lane], acc[e]);
    }
#pragma unroll
    for (int e = 0; e < NEXP; ++e) {
        float v = acc[e];
#pragma unroll
        for (int off = 32; off; off >>= 1) v += __shfl_xor(v, off);
        acc[e] = v;
    }
    if (lane < NEXP) out_logits[(size_t)t * NEXP + lane] = acc[lane];

    if (lane == 0) {
        float mx = acc[0];
#pragma unroll
        for (int e = 1; e < NEXP; ++e) mx = fmaxf(mx, acc[e]);
        float p[NEXP], s = 0.f;
#pragma unroll
        for (int e = 0; e < NEXP; ++e) { p[e] = expf(acc[e] - mx); s += p[e]; }
        const float inv = 1.f / s;
#pragma unroll
        for (int e = 0; e < NEXP; ++e) p[e] *= inv;

        int s1 = 0; float v1 = p[0] + bias[0];
#pragma unroll
        for (int e = 1; e < NEXP; ++e) {
            float c = p[e] + bias[e];
            if (c > v1) { v1 = c; s1 = e; }
        }
        int s2 = -1; float v2 = -1e30f;
#pragma unroll
        for (int e = 0; e < NEXP; ++e) {
            if (e == s1) continue;
            float c = p[e] + bias[e];
            if (c > v2) { v2 = c; s2 = e; }
        }
        float w1 = p[s1], w2 = p[s2];
        float sw = fmaxf(w1 + w2, 1e-12f);
        w1 /= sw; w2 /= sw;

        const int base = vis ? NEXP : 0;
        int pos1 = atomicAdd(&counts[base + s1], 1);
        lists[(base + s1) * TOK + pos1] = t * 2 + 0;
        wlist[(base + s1) * TOK + pos1] = w1;
        int pos2 = atomicAdd(&counts[base + s2], 1);
        lists[(base + s2) * TOK + pos2] = t * 2 + 1;
        wlist[(base + s2) * TOK + pos2] = w2;
    }
}

// ---------------- weight convert/swizzle: fp32 [K][N] -> bf16 fragments ----
// (R5 version: 2 panels/block pipelined, NT fp32 reads, pack-before-LDS.)
__device__ __forceinline__ void conv_decode(
    int bid,
    const float* gut, const float* guv, const float* dnt, const float* dnv,
    const float* sg, const float* su, const float* sd, unsigned short* sw,
    const float*& src, unsigned short*& dst, int& K, int& N, int& c, int& p)
{
    if (bid < 2048)      { int i = bid;        int e = i >> 7, r = i & 127; c = r >> 2; p = r & 3; K = 1024; N = 1024; src = gut + (size_t)e * 1048576; dst = sw + SW_GUT + (size_t)e * 1048576; }
    else if (bid < 3072) { int i = bid - 2048; int e = i >> 6, r = i & 63;  c = r >> 1; p = r & 1; K = 1024; N = 512;  src = guv + (size_t)e * 524288;  dst = sw + SW_GUV + (size_t)e * 524288; }
    else if (bid < 4096) { int i = bid - 3072; int e = i >> 6, r = i & 63;  c = r >> 2; p = r & 3; K = 512;  N = 1024; src = dnt + (size_t)e * 524288;  dst = sw + SW_DNT + (size_t)e * 524288; }
    else if (bid < 4608) { int i = bid - 4096; int e = i >> 5, r = i & 31;  c = r >> 2; p = r & 3; K = 256;  N = 1024; src = dnv + (size_t)e * 262144;  dst = sw + SW_DNV + (size_t)e * 262144; }
    else if (bid < 4736) { int i = bid - 4608; c = i >> 2; p = i & 3; K = 1024; N = 1024; src = sg; dst = sw + SW_SG; }
    else if (bid < 4864) { int i = bid - 4736; c = i >> 2; p = i & 3; K = 1024; N = 1024; src = su; dst = sw + SW_SU; }
    else                 { int i = bid - 4864; c = i >> 2; p = i & 3; K = 1024; N = 1024; src = sd; dst = sw + SW_SD; }
}

__global__ __launch_bounds__(256)
void k_conv(const float* __restrict__ gut, const float* __restrict__ guv,
            const float* __restrict__ dnt, const float* __restrict__ dnv,
            const float* __restrict__ sg, const float* __restrict__ su,
            const float* __restrict__ sd, unsigned short* __restrict__ sw)
{
    __shared__ unsigned ls[16 * 258];
    const int tid = threadIdx.x;
    const int b0 = blockIdx.x * 2;

    const float *sA, *sB; unsigned short *dA, *dB;
    int KA, NA, cA, pA, KB, NB, cB, pB;
    conv_decode(b0 + 0, gut, guv, dnt, dnv, sg, su, sd, sw, sA, dA, KA, NA, cA, pA);
    conv_decode(b0 + 1, gut, guv, dnt, dnv, sg, su, sd, sw, sB, dB, KB, NB, cB, pB);

    f32x4 Ra[8], Rb[8];
#pragma unroll
    for (int i = 0; i < 4; ++i) {
        int u = tid + i * 256; int kp = u >> 6, c4 = u & 63;
        const float* r0 = sA + (size_t)(cA * 32 + 2 * kp) * NA + pA * 256 + c4 * 4;
        Ra[2 * i]     = ntload4(r0);
        Ra[2 * i + 1] = ntload4(r0 + NA);
    }
#pragma unroll
    for (int i = 0; i < 4; ++i) {
        int u = tid + i * 256; int kp = u >> 6, c4 = u & 63;
        const float* r0 = sB + (size_t)(cB * 32 + 2 * kp) * NB + pB * 256 + c4 * 4;
        Rb[2 * i]     = ntload4(r0);
        Rb[2 * i + 1] = ntload4(r0 + NB);
    }

    // ---- panel A ----
#pragma unroll
    for (int i = 0; i < 4; ++i) {
        int u = tid + i * 256; int kp = u >> 6, c4 = u & 63;
        unsigned* lp = &ls[kp * 258 + c4 * 4];
        f32x4 a = Ra[2 * i], b = Ra[2 * i + 1];
        lp[0] = pack2(a[0], b[0]); lp[1] = pack2(a[1], b[1]);
        lp[2] = pack2(a[2], b[2]); lp[3] = pack2(a[3], b[3]);
    }
    __syncthreads();
    {
        const int KC = KA >> 5;
#pragma unroll
        for (int i = 0; i < 4; ++i) {
            int u = tid + i * 256;
            int tt = u >> 6, l = u & 63;
            int q = l >> 4, lm = l & 15;
            int col = tt * 16 + lm;
            unsigned d0 = ls[(q * 4 + 0) * 258 + col];
            unsigned d1 = ls[(q * 4 + 1) * 258 + col];
            unsigned d2 = ls[(q * 4 + 2) * 258 + col];
            unsigned d3 = ls[(q * 4 + 3) * 258 + col];
            size_t off = ((size_t)((pA * 16 + tt) * KC + cA) * 64 + l) * 8;
            *(uint4*)(dA + off) = make_uint4(d0, d1, d2, d3);
        }
    }
    __syncthreads();

    // ---- panel B ----
#pragma unroll
    for (int i = 0; i < 4; ++i) {
        int u = tid + i * 256; int kp = u >> 6, c4 = u & 63;
        unsigned* lp = &ls[kp * 258 + c4 * 4];
        f32x4 a = Rb[2 * i], b = Rb[2 * i + 1];
        lp[0] = pack2(a[0], b[0]); lp[1] = pack2(a[1], b[1]);
        lp[2] = pack2(a[2], b[2]); lp[3] = pack2(a[3], b[3]);
    }
    __syncthreads();
    {
        const int KC = KB >> 5;
#pragma unroll
        for (int i = 0; i < 4; ++i) {
            int u = tid + i * 256;
            int tt = u >> 6, l = u & 63;
            int q = l >> 4, lm = l & 15;
            int col = tt * 16 + lm;
            unsigned d0 = ls[(q * 4 + 0) * 258 + col];
            unsigned d1 = ls[(q * 4 + 1) * 258 + col];
            unsigned d2 = ls[(q * 4 + 2) * 258 + col];
            unsigned d3 = ls[(q * 4 + 3) * 258 + col];
            size_t off = ((size_t)((pB * 16 + tt) * KC + cB) * 64 + l) * 8;
            *(uint4*)(dB + off) = make_uint4(d0, d1, d2, d3);
        }
    }
}

// ---------------- gate+up GEMM + silu: DMA-staged B, M-split waves ---------
// Block 64 tokens x 16 i-cols; wave w = rows [16w,16w+16). B (G+U, full K)
// is DMA'd to LDS up front (wave w issues chunks c%4==w; 16 instrs -> 32 KB
// in flight per wave, 64 KB per block), ONE barrier drain, then MFMA loop
// reads conflict-free ds_read_b128 + 2-deep A register prefetch.
__global__ __launch_bounds__(256)
void k_gu4(const unsigned short* __restrict__ Xbf, const unsigned short* __restrict__ sw,
           const int* __restrict__ counts, const int* __restrict__ lists,
           unsigned short* __restrict__ hbuf, unsigned short* __restrict__ hsh)
{
    const int z = blockIdx.z;
    int M, I, utile0;
    const unsigned short *gbase, *ubase;
    if (z == 32)      { M = TOK;       I = 1024; gbase = sw + SW_SG; ubase = sw + SW_SU; utile0 = 0; }
    else if (z < 16)  { M = counts[z]; I = 512;  gbase = ubase = sw + SW_GUT + (size_t)z * 1048576; utile0 = 32; }
    else              { M = counts[z]; I = 256;  gbase = ubase = sw + SW_GUV + (size_t)(z - 16) * 524288; utile0 = 16; }
    const int xI = blockIdx.x * 16, m0 = blockIdx.y * 64;
    if (xI >= I || m0 >= M) return;

    __shared__ unsigned short lsB[32768];      // G: [0,16384) | U: [16384,32768)
    __shared__ int s_aid[64];
    const int tid = threadIdx.x;
    const int w = tid >> 6, lane = tid & 63;

    const int tg = xI >> 4;
    const unsigned short* gsrc = gbase + (size_t)tg * 16384;
    const unsigned short* usrc = ubase + (size_t)(utile0 + tg) * 16384;
    for (int c = w; c < 32; c += 4) {
        lds_dma16(gsrc + ((size_t)c * 64 + lane) * 8, &lsB[c * 512]);
        lds_dma16(usrc + ((size_t)c * 64 + lane) * 8, &lsB[16384 + c * 512]);
    }
    if (tid < 64) {
        int r = m0 + tid;
        s_aid[tid] = (z == 32) ? r : ((r < M) ? lists[z * TOK + r] : -1);
    }
    __syncthreads();                           // single drain: 64 KB was in flight

    const int lm = lane & 15, q = lane >> 4, ko = q * 8;
    int aidA = s_aid[w * 16 + lm];
    int tr = (z == 32) ? aidA : (aidA < 0 ? 0 : (aidA >> 1));
    const unsigned short* arow = Xbf + (size_t)tr * HID;

    f32x4 accG = {}, accU = {};
    bf16x8 A0 = *(const bf16x8*)(arow + ko);
    const unsigned short* lg = &lsB[lane * 8];
    const unsigned short* lu = &lsB[16384 + lane * 8];
#pragma unroll 8
    for (int c = 0; c < 32; ++c) {
        bf16x8 bg = *(const bf16x8*)(lg + c * 512);
        bf16x8 bu = *(const bf16x8*)(lu + c * 512);
        bf16x8 An = A0;
        if (c + 1 < 32) An = *(const bf16x8*)(arow + (c + 1) * 32 + ko);
        accG = __builtin_amdgcn_mfma_f32_16x16x32_bf16(A0, bg, accG, 0, 0, 0);
        accU = __builtin_amdgcn_mfma_f32_16x16x32_bf16(A0, bu, accU, 0, 0, 0);
        A0 = An;
    }

    const int i = xI + lm;
#pragma unroll
    for (int r = 0; r < 4; ++r) {
        int row = w * 16 + q * 4 + r;
        int aid = s_aid[row];
        if (aid < 0) continue;
        float g = accG[r], uu = accU[r];
        float h = g / (1.f + __expf(-g)) * uu;
        if (z == 32) hsh[(size_t)aid * 1024 + i] = f2bf(h);
        else         hbuf[(size_t)aid * 512 + i] = f2bf(h);
    }
}

// ---------------- down GEMM: DMA-staged B, M-split waves -------------------
__global__ __launch_bounds__(256)
void k_down4(const unsigned short* __restrict__ hbuf, const unsigned short* __restrict__ hsh,
             const unsigned short* __restrict__ sw,
             const int* __restrict__ counts, const int* __restrict__ lists,
             const float* __restrict__ wlist, float* __restrict__ out)
{
    const int z = blockIdx.z;
    int M, K;
    const unsigned short* base;
    if (z == 32)     { M = TOK;       K = 1024; base = sw + SW_SD; }
    else if (z < 16) { M = counts[z]; K = 512;  base = sw + SW_DNT + (size_t)z * 524288; }
    else             { M = counts[z]; K = 256;  base = sw + SW_DNV + (size_t)(z - 16) * 262144; }
    const int n0 = blockIdx.x * 16, m0 = blockIdx.y * 64;
    if (m0 >= M) return;

    __shared__ unsigned short lsB[16384];      // up to 32 chunks x 1 KB
    __shared__ int s_aid[64];
    __shared__ float s_w[64];
    const int tid = threadIdx.x;
    const int w = tid >> 6, lane = tid & 63;
    const int KC = K >> 5;

    const unsigned short* src = base + (size_t)blockIdx.x * KC * 512;
    for (int c = w; c < KC; c += 4)
        lds_dma16(src + ((size_t)c * 64 + lane) * 8, &lsB[c * 512]);

    if (tid < 64) {
        int r = m0 + tid;
        if (z == 32)    { s_aid[tid] = r; s_w[tid] = 1.f; }
        else if (r < M) { s_aid[tid] = lists[z * TOK + r]; s_w[tid] = wlist[z * TOK + r]; }
        else            { s_aid[tid] = -1; s_w[tid] = 0.f; }
    }
    __syncthreads();

    const int lm = lane & 15, q = lane >> 4, ko = q * 8;
    int aidA = s_aid[w * 16 + lm];
    const unsigned short* hrow = (z == 32) ? (hsh + (size_t)aidA * 1024)
                                           : (hbuf + (size_t)(aidA < 0 ? 0 : aidA) * 512);

    f32x4 acc = {};
    bf16x8 A0 = *(const bf16x8*)(hrow + ko);
    const unsigned short* lb = &lsB[lane * 8];
    for (int c = 0; c < KC; ++c) {
        bf16x8 bt = *(const bf16x8*)(lb + c * 512);
        bf16x8 An = A0;
        if (c + 1 < KC) An = *(const bf16x8*)(hrow + (c + 1) * 32 + ko);
        acc = __builtin_amdgcn_mfma_f32_16x16x32_bf16(A0, bt, acc, 0, 0, 0);
        A0 = An;
    }

    const int col = n0 + lm;
#pragma unroll
    for (int r = 0; r < 4; ++r) {
        int row = w * 16 + q * 4 + r;
        int aid = s_aid[row];
        if (aid < 0) continue;
        int tok = (z == 32) ? aid : (aid >> 1);
        atomicAdd(&out[(size_t)tok * HID + col], s_w[row] * acc[r]);
    }
}

// ================= fallback path (small ws): r5 kernels, uncapped bounds ===
__global__ __launch_bounds__(256)
void k_gu_fb(const unsigned short* __restrict__ Xbf,
             const float* __restrict__ gut, const float* __restrict__ guv,
             const float* __restrict__ sg, const float* __restrict__ su,
             const int* __restrict__ counts, const int* __restrict__ lists,
             unsigned short* __restrict__ hbuf, unsigned short* __restrict__ hsh)
{
    const int z = blockIdx.z;
    int M, I, str;
    const float *Wg, *Wu;
    if (z == 32) { M = TOK; I = 1024; str = 1024; Wg = sg; Wu = su; }
    else {
        M = counts[z];
        const int mod = z >> 4, e = z & 15;
        I = mod ? 256 : 512; str = 2 * I;
        const float* base = mod ? (guv + (size_t)e * HID * 512)
                                : (gut + (size_t)e * HID * 1024);
        Wg = base; Wu = base + I;
    }
    const int xI = blockIdx.x * 64;
    const int m0 = blockIdx.y * 64;
    if (xI >= I || m0 >= M) return;

    __shared__ float bs[8192];
    __shared__ int s_aid[64];
    const int tid = threadIdx.x;
    const int wid = tid >> 6, lane = tid & 63;
    const int lm = lane & 15, q = lane >> 4;

    if (tid < 64) {
        int r = m0 + tid;
        s_aid[tid] = (z == 32) ? r : ((r < M) ? lists[z * TOK + r] : -1);
    }
    __syncthreads();

    const unsigned short* arow[4];
#pragma unroll
    for (int s = 0; s < 4; ++s) {
        int aid = s_aid[s * 16 + lm];
        int tr = (z == 32) ? aid : (aid < 0 ? 0 : (aid >> 1));
        arow[s] = Xbf + (size_t)tr * HID;
    }
    int urow[8], uc4[8], scell[8];
#pragma unroll
    for (int r = 0; r < 8; ++r) {
        int u = r * 256 + tid;
        int k = u >> 5;
        urow[r] = k; uc4[r] = u & 31;
        scell[r] = k * 32 + ((u & 31) ^ (((k >> 3) & 1) << 2));
    }
    int fidx[2];
#pragma unroll
    for (int reg = 0; reg < 2; ++reg) {
        int c = reg * 64 + wid * 16 + lm;
        fidx[reg] = (q * 8) * 128 + (((c >> 2) ^ ((q & 1) << 2)) * 4 + (c & 3));
    }
    float4 R[8];
#pragma unroll
    for (int r = 0; r < 8; ++r) {
        int c4 = uc4[r];
        const float* gp = (c4 < 16) ? (Wg + (size_t)urow[r] * str + xI + c4 * 4)
                                    : (Wu + (size_t)urow[r] * str + xI + (c4 - 16) * 4);
        R[r] = *(const float4*)gp;
    }
    f32x4 accG[4] = {}, accU[4] = {};
    for (int kc = 0; kc < 16; ++kc) {
        if (kc) __syncthreads();
#pragma unroll
        for (int r = 0; r < 8; ++r)
            *(float4*)&bs[scell[r] * 4] = R[r];
        __syncthreads();
        bf16x8 af[2][4];
        const int kg = kc * 64 + q * 8;
#pragma unroll
        for (int s = 0; s < 4; ++s) {
            af[0][s] = *(const bf16x8*)(arow[s] + kg);
            af[1][s] = *(const bf16x8*)(arow[s] + kg + 32);
        }
        if (kc + 1 < 16) {
            const int k0 = (kc + 1) * 64;
#pragma unroll
            for (int r = 0; r < 8; ++r) {
                int c4 = uc4[r];
                const float* gp = (c4 < 16) ? (Wg + (size_t)(k0 + urow[r]) * str + xI + c4 * 4)
                                            : (Wu + (size_t)(k0 + urow[r]) * str + xI + (c4 - 16) * 4);
                R[r] = *(const float4*)gp;
            }
        }
#pragma unroll
        for (int ks2 = 0; ks2 < 2; ++ks2) {
            const int ks = ks2 * 32;
            bf16x8 bg, bu;
            {
                float b[8];
#pragma unroll
                for (int j = 0; j < 8; ++j) b[j] = bs[fidx[0] + (ks + j) * 128];
                union { bf16x8 v; unsigned d[4]; } u;
                u.d[0] = pack2(b[0], b[1]); u.d[1] = pack2(b[2], b[3]);
                u.d[2] = pack2(b[4], b[5]); u.d[3] = pack2(b[6], b[7]);
                bg = u.v;
            }
            {
                float b[8];
#pragma unroll
                for (int j = 0; j < 8; ++j) b[j] = bs[fidx[1] + (ks + j) * 128];
                union { bf16x8 v; unsigned d[4]; } u;
                u.d[0] = pack2(b[0], b[1]); u.d[1] = pack2(b[2], b[3]);
                u.d[2] = pack2(b[4], b[5]); u.d[3] = pack2(b[6], b[7]);
                bu = u.v;
            }
#pragma unroll
            for (int s = 0; s < 4; ++s) {
                accG[s] = __builtin_amdgcn_mfma_f32_16x16x32_bf16(af[ks2][s], bg, accG[s], 0, 0, 0);
                accU[s] = __builtin_amdgcn_mfma_f32_16x16x32_bf16(af[ks2][s], bu, accU[s], 0, 0, 0);
            }
        }
    }
    const int i = xI + wid * 16 + lm;
#pragma unroll
    for (int s = 0; s < 4; ++s)
#pragma unroll
        for (int r = 0; r < 4; ++r) {
            int row = s * 16 + q * 4 + r;
            int aid = s_aid[row];
            if (aid < 0) continue;
            float g = accG[s][r], uu = accU[s][r];
            float h = g / (1.f + __expf(-g)) * uu;
            if (z == 32) hsh[(size_t)aid * 1024 + i] = f2bf(h);
            else         hbuf[(size_t)aid * 512 + i] = f2bf(h);
        }
}

__global__ __launch_bounds__(256)
void k_down_fb(const unsigned short* __restrict__ hbuf, const unsigned short* __restrict__ hsh,
               const float* __restrict__ dnt, const float* __restrict__ dnv,
               const float* __restrict__ sd,
               const int* __restrict__ counts, const int* __restrict__ lists,
               const float* __restrict__ wlist, float* __restrict__ out)
{
    const int z = blockIdx.z;
    int M, K;
    const float* W;
    if (z == 32) { M = TOK; K = 1024; W = sd; }
    else {
        M = counts[z];
        const int mod = z >> 4, e = z & 15;
        K = mod ? 256 : 512;
        W = mod ? (dnv + (size_t)e * 256 * 1024) : (dnt + (size_t)e * 512 * 1024);
    }
    const int n0 = blockIdx.x * 128;
    const int m0 = blockIdx.y * 64;
    if (m0 >= M) return;

    __shared__ float bs[8192];
    __shared__ int s_aid[64];
    __shared__ float s_w[64];
    const int tid = threadIdx.x;
    const int wid = tid >> 6, lane = tid & 63;
    const int lm = lane & 15, q = lane >> 4;

    if (tid < 64) {
        int r = m0 + tid;
        if (z == 32)    { s_aid[tid] = r; s_w[tid] = 1.f; }
        else if (r < M) { s_aid[tid] = lists[z * TOK + r]; s_w[tid] = wlist[z * TOK + r]; }
        else            { s_aid[tid] = -1; s_w[tid] = 0.f; }
    }
    __syncthreads();

    const unsigned short* hrow[4];
#pragma unroll
    for (int s = 0; s < 4; ++s) {
        int aid = s_aid[s * 16 + lm];
        hrow[s] = (z == 32) ? (hsh + (size_t)aid * 1024)
                            : (hbuf + (size_t)(aid < 0 ? 0 : aid) * 512);
    }
    int urow[8], uc4[8], scell[8];
#pragma unroll
    for (int r = 0; r < 8; ++r) {
        int u = r * 256 + tid;
        int k = u >> 5;
        urow[r] = k; uc4[r] = u & 31;
        scell[r] = k * 32 + ((u & 31) ^ (((k >> 3) & 1) << 2));
    }
    int fidx[2];
#pragma unroll
    for (int t = 0; t < 2; ++t) {
        int c = wid * 32 + t * 16 + lm;
        fidx[t] = (q * 8) * 128 + (((c >> 2) ^ ((q & 1) << 2)) * 4 + (c & 3));
    }
    float4 R[8];
#pragma unroll
    for (int r = 0; r < 8; ++r)
        R[r] = *(const float4*)(W + (size_t)urow[r] * 1024 + n0 + uc4[r] * 4);

    f32x4 acc[4][2] = {};
    const int NC = K >> 6;
    for (int kc = 0; kc < NC; ++kc) {
        if (kc) __syncthreads();
#pragma unroll
        for (int r = 0; r < 8; ++r)
            *(float4*)&bs[scell[r] * 4] = R[r];
        __syncthreads();
        bf16x8 af[2][4];
        const int kg = kc * 64 + q * 8;
#pragma unroll
        for (int s = 0; s < 4; ++s) {
            af[0][s] = *(const bf16x8*)(hrow[s] + kg);
            af[1][s] = *(const bf16x8*)(hrow[s] + kg + 32);
        }
        if (kc + 1 < NC) {
            const int k0 = (kc + 1) * 64;
#pragma unroll
            for (int r = 0; r < 8; ++r)
                R[r] = *(const float4*)(W + (size_t)(k0 + urow[r]) * 1024 + n0 + uc4[r] * 4);
        }
#pragma unroll
        for (int ks2 = 0; ks2 < 2; ++ks2) {
            const int ks = ks2 * 32;
            bf16x8 bt[2];
#pragma unroll
            for (int t = 0; t < 2; ++t) {
                float b[8];
#pragma unroll
                for (int j = 0; j < 8; ++j) b[j] = bs[fidx[t] + (ks + j) * 128];
                union { bf16x8 v; unsigned d[4]; } u;
                u.d[0] = pack2(b[0], b[1]); u.d[1] = pack2(b[2], b[3]);
                u.d[2] = pack2(b[4], b[5]); u.d[3] = pack2(b[6], b[7]);
                bt[t] = u.v;
            }
#pragma unroll
            for (int s = 0; s < 4; ++s)
#pragma unroll
                for (int t = 0; t < 2; ++t)
                    acc[s][t] = __builtin_amdgcn_mfma_f32_16x16x32_bf16(af[ks2][s], bt[t], acc[s][t], 0, 0, 0);
        }
    }
#pragma unroll
    for (int s = 0; s < 4; ++s)
#pragma unroll
        for (int r = 0; r < 4; ++r) {
            int row = s * 16 + q * 4 + r;
            int aid = s_aid[row];
            if (aid < 0) continue;
            int tok = (z == 32) ? aid : (aid >> 1);
            float w = s_w[row];
#pragma unroll
            for (int t = 0; t < 2; ++t) {
                int col = n0 + wid * 32 + t * 16 + lm;
                atomicAdd(&out[(size_t)tok * HID + col], w * acc[s][t][r]);
            }
        }
}

extern "C" void kernel_launch(void* const* d_in, const int* in_sizes, int n_in,
                              void* d_out, int out_size, void* d_ws, size_t ws_size,
                              hipStream_t stream)
{
    const float* x    = (const float*)d_in[0];
    const int*   tt   = (const int*)d_in[1];
    const float* rw_t = (const float*)d_in[2];
    const float* b_t  = (const float*)d_in[3];
    const float* gu_t = (const float*)d_in[4];
    const float* dn_t = (const float*)d_in[5];
    const float* rw_v = (const float*)d_in[6];
    const float* b_v  = (const float*)d_in[7];
    const float* gu_v = (const float*)d_in[8];
    const float* dn_v = (const float*)d_in[9];
    const float* sg   = (const float*)d_in[10];
    const float* su   = (const float*)d_in[11];
    const float* sd   = (const float*)d_in[12];
    float* out = (float*)d_out;
    float* out_logits = out + (size_t)TOK * HID;

    char* ws = (char*)d_ws;
    int*   counts = (int*)ws;                                   // 32 ints
    int*   lists  = (int*)(ws + 1024);                          // 32*1024 ints
    float* wlist  = (float*)(ws + 1024 + 32 * TOK * 4);         // 32*1024 floats
    unsigned short* hbuf = (unsigned short*)(ws + 1024 + 64 * TOK * 4);  // 2048x512 bf16
    unsigned short* hsh  = hbuf + (size_t)2048 * 512;                    // 1024x1024 bf16
    unsigned short* Xbf  = hsh + (size_t)1024 * 1024;                    // 1024x1024 bf16
    unsigned short* swz  = Xbf + (size_t)1024 * 1024;                    // 78 MB swizzled weights

    hipLaunchKernelGGL(k_init, dim3(1024), dim3(256), 0, stream, out, counts);
    hipLaunchKernelGGL(k_router, dim3(TOK), dim3(64), 0, stream,
                       x, tt, rw_t, b_t, rw_v, b_v, out_logits, counts, lists, wlist, Xbf);
    if (ws_size >= WS_FAST) {
        hipLaunchKernelGGL(k_conv, dim3(2496), dim3(256), 0, stream,
                           gu_t, gu_v, dn_t, dn_v, sg, su, sd, swz);
        hipLaunchKernelGGL(k_gu4, dim3(64, 16, 33), dim3(256), 0, stream,
                           Xbf, swz, counts, lists, hbuf, hsh);
        hipLaunchKernelGGL(k_down4, dim3(64, 16, 33), dim3(256), 0, stream,
                           hbuf, hsh, swz, counts, lists, wlist, out);
    } else {
        hipLaunchKernelGGL(k_gu_fb, dim3(16, 16, 33), dim3(256), 0, stream,
                           Xbf, gu_t, gu_v, sg, su, counts, lists, hbuf, hsh);
        hipLaunchKernelGGL(k_down_fb, dim3(8, 16, 33), dim3(256), 0, stream,
                           hbuf, hsh, dn_t, dn_v, sd, counts, lists, wlist, out);
    }
}